// Round 4
// baseline (333.956 us; speedup 1.0000x reference)
//
#include <hip/hip_runtime.h>
#include <cmath>

// ---------------------------------------------------------------------------
// PatchTST encoder layer w/ p-RoPE, MI355X (gfx950).  Round 11:
//  - GEMMs/prep/LN unchanged.
//  - flash v6: latency-targeted rework of v5 (v5's VALU diet exposed the
//    1-iter-deep prefetch: dur 51.6->66.2 despite VALUBusy 58->29).
//    * V moves to REGISTERS: the PV B-fragment V[s=quad*8+j][d=nt*16+l15]
//      is per-lane contiguous 16B in vt -> 4 global_load_dwordx4 per pair,
//      no LDS, no swizzle, no bank conflicts, shorter latency path.
//    * K stays g2l->LDS but 4 slots deep ([4][1024] per wave).
//    * Loop over 16 PAIRS: issue K(pair j+1) + V(pair j+1), single
//      s_waitcnt vmcnt(8) drains pair j -> prefetch slack = one full pair
//      body (2x v5).  vfA/vfB reg double-buffer via 2-pair unroll.
//    * LDS 50176 -> 33792 B; K slots reused as epilogue O-partial region.
// Fragment layouts (verified, guide §3, 16x16x32 only):
//   A[m=lane&15][k=quad*8+j]; B[k=quad*8+j][n=lane&15];
//   C/D col=lane&15, row=quad*4+reg.   (A and B lane maps are identical, so
//   swapping MFMA operands transposes C with no fragment-read change.)
// ---------------------------------------------------------------------------

typedef __bf16 bf16_t;
typedef bf16_t bf16x8 __attribute__((ext_vector_type(8)));
typedef float floatx4 __attribute__((ext_vector_type(4)));
typedef unsigned int u32x4 __attribute__((ext_vector_type(4)));

#define MFMA(a, b, c) __builtin_amdgcn_mfma_f32_16x16x32_bf16((a), (b), (c), 0, 0, 0)
#define LOG2E 1.44269504088896340736f

__device__ __forceinline__ bf16_t f2bf(float f) { return (bf16_t)f; }

__device__ __forceinline__ float fexp2(float x) {
  return __builtin_amdgcn_exp2f(x);  // raw v_exp_f32
}

__device__ __forceinline__ void g2l16(const void* g, void* l) {
  __builtin_amdgcn_global_load_lds(
      (const __attribute__((address_space(1))) unsigned int*)g,
      (__attribute__((address_space(3))) unsigned int*)l, 16, 0, 0);
}

__device__ __forceinline__ void wait_vm8() {
  asm volatile("s_waitcnt vmcnt(8)" ::: "memory");
}
__device__ __forceinline__ void wait_vm0() {
  asm volatile("s_waitcnt vmcnt(0)" ::: "memory");
}

// pack two f32 -> bf16x2 (lo = first operand)
__device__ __forceinline__ unsigned cvt_pk_bf16(float lo, float hi) {
  unsigned r;
  asm("v_cvt_pk_bf16_f32 %0, %1, %2" : "=v"(r) : "v"(lo), "v"(hi));
  return r;
}
// swap rows(16-lane groups): a.row{2,3} <-> b.row{0,1}
__device__ __forceinline__ void pl32swap(unsigned& a, unsigned& b) {
  asm("v_permlane32_swap_b32 %0, %1" : "+v"(a), "+v"(b));
}
// swap a.row{1,3} <-> b.row{0,2}
__device__ __forceinline__ void pl16swap(unsigned& a, unsigned& b) {
  asm("v_permlane16_swap_b32 %0, %1" : "+v"(a), "+v"(b));
}

// ---------------------------------------------------------------------------
// k_prep: all weight transposes (fp32 [R][C] -> bf16 [C][R]) + LN1, one grid.
// ---------------------------------------------------------------------------
struct PrepP {
  const float *wq, *wk, *wv, *wo, *w1, *w2;
  bf16_t *wqkvT, *woT, *w1T, *w2T;
  const float *hs, *g1, *be1;
  bf16_t* ni;
};

__global__ __launch_bounds__(256) void k_prep(PrepP p) {
  __shared__ float shm[32 * 33];
  const int bid = blockIdx.x;
  if (bid < 6912) {
    const float* in;
    bf16_t* out;
    int R, C, tx, ty;
    if (bid < 2304) {
      int m = bid / 576, lo = bid % 576;
      in = (m == 0) ? p.wq : (m == 1) ? p.wk : (m == 2) ? p.wv : p.wo;
      out = (m < 3) ? p.wqkvT + (size_t)m * 768 * 768 : p.woT;
      R = 768; C = 768; tx = lo % 24; ty = lo / 24;
    } else if (bid < 4608) {
      int lo = bid - 2304;
      in = p.w1; out = p.w1T; R = 768; C = 3072; tx = lo % 96; ty = lo / 96;
    } else {
      int lo = bid - 4608;
      in = p.w2; out = p.w2T; R = 3072; C = 768; tx = lo % 24; ty = lo / 24;
    }
    const int c0 = tx * 32, r0 = ty * 32;
    const int lx = threadIdx.x & 31, ly = threadIdx.x >> 5;
#pragma unroll
    for (int p4 = 0; p4 < 4; p4++) {
      int r = ly + p4 * 8;
      shm[r * 33 + lx] = in[(size_t)(r0 + r) * C + c0 + lx];
    }
    __syncthreads();
#pragma unroll
    for (int p4 = 0; p4 < 4; p4++) {
      int r = ly + p4 * 8;
      out[(size_t)(c0 + r) * R + r0 + lx] = f2bf(shm[lx * 33 + r]);
    }
  } else {
    const int row = bid - 6912;
    const float* xr = p.hs + (size_t)row * 768;
    const int t = threadIdx.x;
    float v0 = xr[t], v1 = xr[t + 256], v2 = xr[t + 512];
    float s = v0 + v1 + v2;
    float s2 = v0 * v0 + v1 * v1 + v2 * v2;
#pragma unroll
    for (int off = 32; off; off >>= 1) {
      s += __shfl_xor(s, off);
      s2 += __shfl_xor(s2, off);
    }
    const int w = t >> 6;
    if ((t & 63) == 0) { shm[w] = s; shm[4 + w] = s2; }
    __syncthreads();
    s = shm[0] + shm[1] + shm[2] + shm[3];
    s2 = shm[4] + shm[5] + shm[6] + shm[7];
    const float mu = s * (1.0f / 768.0f);
    const float var = s2 * (1.0f / 768.0f) - mu * mu;
    const float rstd = rsqrtf(var + 1e-5f);
    bf16_t* orow = p.ni + (size_t)row * 768;
    orow[t]       = f2bf((v0 - mu) * rstd * p.g1[t]       + p.be1[t]);
    orow[t + 256] = f2bf((v1 - mu) * rstd * p.g1[t + 256] + p.be1[t + 256]);
    orow[t + 512] = f2bf((v2 - mu) * rstd * p.g1[t + 512] + p.be1[t + 512]);
  }
}

// ---------------------------------------------------------------------------
// LayerNorm (LN3): fp32 in -> bf16 out, one block per row.
// ---------------------------------------------------------------------------
__global__ __launch_bounds__(256) void k_layernorm(
    const float* __restrict__ x, const float* __restrict__ g,
    const float* __restrict__ b, bf16_t* __restrict__ out) {
  const int row = blockIdx.x;
  const float* xr = x + (size_t)row * 768;
  const int t = threadIdx.x;
  float v0 = xr[t], v1 = xr[t + 256], v2 = xr[t + 512];
  float s = v0 + v1 + v2;
  float s2 = v0 * v0 + v1 * v1 + v2 * v2;
#pragma unroll
  for (int off = 32; off; off >>= 1) {
    s += __shfl_xor(s, off);
    s2 += __shfl_xor(s2, off);
  }
  __shared__ float ra[4], rb[4];
  const int w = t >> 6;
  if ((t & 63) == 0) { ra[w] = s; rb[w] = s2; }
  __syncthreads();
  s = ra[0] + ra[1] + ra[2] + ra[3];
  s2 = rb[0] + rb[1] + rb[2] + rb[3];
  const float mu = s * (1.0f / 768.0f);
  const float var = s2 * (1.0f / 768.0f) - mu * mu;
  const float rstd = rsqrtf(var + 1e-5f);
  bf16_t* orow = out + (size_t)row * 768;
  orow[t]       = f2bf((v0 - mu) * rstd * g[t]       + b[t]);
  orow[t + 256] = f2bf((v1 - mu) * rstd * g[t + 256] + b[t + 256]);
  orow[t + 512] = f2bf((v2 - mu) * rstd * g[t + 512] + b[t + 512]);
}

// ---------------------------------------------------------------------------
// 128x128-tile bf16 MFMA GEMM (QKV mode 0, FFN1 mode 2). m97 structure (r5).
// ---------------------------------------------------------------------------
struct GemmP {
  const bf16_t* A;
  const bf16_t* Bt;
  int M, N, K, mode;
  const float* bias0;
  const float* bias1;
  const float* bias2;
  float* outF;
  bf16_t* outB0;
  bf16_t* outB1;
  bf16_t* outB2;
};

__global__ __launch_bounds__(256, 3) void k_gemm(GemmP p) {
  __shared__ bf16_t lds[18432];  // 36 KiB
  const int tid = threadIdx.x;
  const int lane = tid & 63, wave = tid >> 6;
  const int quad = lane >> 4, l15 = lane & 15;
  const int wm = (wave >> 1) * 64, wn = (wave & 1) * 64;
  const int m0 = blockIdx.y * 128, n0 = blockIdx.x * 128;

  const char* gA[4];
  const char* gB[4];
#pragma unroll
  for (int pp = 0; pp < 4; pp++) {
    int slot = wave * 256 + pp * 64 + lane;
    int r = slot >> 3;
    int c8 = ((slot & 7) ^ (r & 7)) << 3;
    gA[pp] = (const char*)(p.A + (size_t)(m0 + r) * p.K + c8);
    gB[pp] = (const char*)(p.Bt + (size_t)(n0 + r) * p.K + c8);
  }

  int offA[4], offB[4];
#pragma unroll
  for (int i = 0; i < 4; i++) {
    int ra = wm + i * 16 + l15;
    offA[i] = ra * 64 + ((quad * 8) ^ ((ra & 7) << 3));
    int rb = wn + i * 16 + l15;
    offB[i] = rb * 64 + ((quad * 8) ^ ((rb & 7) << 3));
  }

  const floatx4 z4 = {0.f, 0.f, 0.f, 0.f};
  floatx4 acc[4][4];
#pragma unroll
  for (int i = 0; i < 4; i++)
#pragma unroll
    for (int j = 0; j < 4; j++) acc[i][j] = z4;

  const int KT = p.K >> 6;
  bf16_t* Ad = lds + wave * 2048;
  bf16_t* Bd = lds + 8192 + wave * 2048;

  for (int kt = 0; kt < KT; kt++) {
    const size_t kb = (size_t)kt * 128;
#pragma unroll
    for (int pp = 0; pp < 4; pp++) {
      g2l16(gA[pp] + kb, Ad + pp * 512);
      g2l16(gB[pp] + kb, Bd + pp * 512);
    }
    __syncthreads();
#pragma unroll
    for (int ks = 0; ks < 2; ks++) {
      bf16x8 af[4], bfr[4];
#pragma unroll
      for (int i = 0; i < 4; i++) {
        af[i] = *(const bf16x8*)(lds + (offA[i] ^ (ks * 32)));
        bfr[i] = *(const bf16x8*)(lds + 8192 + (offB[i] ^ (ks * 32)));
      }
#pragma unroll
      for (int i = 0; i < 4; i++)
#pragma unroll
        for (int j = 0; j < 4; j++) acc[i][j] = MFMA(af[i], bfr[j], acc[i][j]);
    }
    __syncthreads();
  }

  char* scr = (char*)lds + wave * 9216;

  if (p.mode == 0) {
    const int gnw = n0 + wn;
    const int region = gnw / 768;  // block-uniform
    const int rem = gnw - region * 768;
    const int h = rem >> 6;
    const int b = (m0 + wm) >> 11;
    const int t0 = (m0 + wm) & 2047;
    const float* bias = (region == 0) ? p.bias0 : (region == 1 ? p.bias1 : p.bias2);
    float bb[4];
#pragma unroll
    for (int j = 0; j < 4; j++) bb[j] = bias[h * 64 + j * 16 + l15];
    bf16_t* sb = (bf16_t*)scr;  // [64][72]
    if (region < 2) {
      const float scale = (region == 0) ? 0.125f * LOG2E : 1.0f;
      const float inv_ts = exp2f(-(float)l15 * (13.287712379549449f / 32.0f));
#pragma unroll
      for (int i = 0; i < 4; i++) {
#pragma unroll
        for (int reg = 0; reg < 4; reg++) {
          int tl = i * 16 + quad * 4 + reg;
          float sn, cs;
          __sincosf((float)(t0 + tl) * inv_ts, &sn, &cs);
          float v0 = (acc[i][0][reg] + bb[0]) * scale;
          float v1 = (acc[i][1][reg] + bb[1]) * scale;
          float v2 = (acc[i][2][reg] + bb[2]) * scale;
          float v3 = (acc[i][3][reg] + bb[3]) * scale;
          sb[tl * 72 + l15]      = f2bf(v0 * cs - v2 * sn);
          sb[tl * 72 + 16 + l15] = f2bf(v1);
          sb[tl * 72 + 32 + l15] = f2bf(v2 * cs + v0 * sn);
          sb[tl * 72 + 48 + l15] = f2bf(v3);
        }
      }
      __syncthreads();
      bf16_t* outp = (region == 0) ? p.outB0 : p.outB1;
      bf16_t* ob = outp + (((size_t)(b * 12 + h) * 2048 + t0) << 6);
#pragma unroll
      for (int pp = 0; pp < 8; pp++) {
        int row = pp * 8 + (lane >> 3), ch = (lane & 7) << 3;
        *(bf16x8*)(ob + row * 64 + ch) = *(const bf16x8*)&sb[row * 72 + ch];
      }
    } else {
#pragma unroll
      for (int i = 0; i < 4; i++)
#pragma unroll
        for (int j = 0; j < 4; j++)
#pragma unroll
          for (int reg = 0; reg < 4; reg++)
            sb[(j * 16 + l15) * 72 + i * 16 + quad * 4 + reg] =
                f2bf(acc[i][j][reg] + bb[j]);
      __syncthreads();
      bf16_t* ob = p.outB2 + (((size_t)(b * 12 + h)) << 17) + t0;
#pragma unroll
      for (int pp = 0; pp < 8; pp++) {
        int d = pp * 8 + (lane >> 3), ch = (lane & 7) << 3;
        *(bf16x8*)(ob + (size_t)d * 2048 + ch) = *(const bf16x8*)&sb[d * 72 + ch];
      }
    }
  } else {  // mode 2: FFN1 + exact GELU -> bf16
    bf16_t* sb = (bf16_t*)scr;  // [64][72]
    float bb[4];
#pragma unroll
    for (int j = 0; j < 4; j++) bb[j] = p.bias0[n0 + wn + j * 16 + l15];
#pragma unroll
    for (int i = 0; i < 4; i++)
#pragma unroll
      for (int j = 0; j < 4; j++)
#pragma unroll
        for (int reg = 0; reg < 4; reg++) {
          int tl = i * 16 + quad * 4 + reg;
          float x = acc[i][j][reg] + bb[j];
          float gv = 0.5f * x * (1.0f + erff(x * 0.70710678118654752f));
          sb[tl * 72 + j * 16 + l15] = f2bf(gv);
        }
    __syncthreads();
#pragma unroll
    for (int pp = 0; pp < 8; pp++) {
      int row = pp * 8 + (lane >> 3), ch = (lane & 7) << 3;
      *(bf16x8*)(p.outB0 + (size_t)(m0 + wm + row) * p.N + n0 + wn + ch) =
          *(const bf16x8*)&sb[row * 72 + ch];
    }
  }
}

// ---------------------------------------------------------------------------
// 64x64-tile GEMM (WO, FFN2): fp32 out = acc + bias + resid.  (r5 version)
// ---------------------------------------------------------------------------
__global__ __launch_bounds__(256, 4) void k_gemm64(
    const bf16_t* __restrict__ A, const bf16_t* __restrict__ Bt, int N, int K,
    const float* __restrict__ bias, const float* __restrict__ resid,
    float* __restrict__ outF) {
  __shared__ bf16_t lds[16384];  // 32 KiB
  const int tid = threadIdx.x;
  const int lane = tid & 63, wave = tid >> 6;
  const int quad = lane >> 4, l15 = lane & 15;
  const int wm = (wave >> 1) * 32, wn = (wave & 1) * 32;
  const int m0 = blockIdx.y * 64, n0 = blockIdx.x * 64;

  const char* gA[4];
  const char* gB[4];
#pragma unroll
  for (int pp = 0; pp < 4; pp++) {
    int slot = wave * 256 + pp * 64 + lane;
    int r = slot >> 4;
    int c = ((slot & 15) ^ (r & 7)) << 3;  // elems
    gA[pp] = (const char*)(A + (size_t)(m0 + r) * K + c);
    gB[pp] = (const char*)(Bt + (size_t)(n0 + r) * K + c);
  }

  const floatx4 z4 = {0.f, 0.f, 0.f, 0.f};
  floatx4 acc[2][2];
#pragma unroll
  for (int i = 0; i < 2; i++)
#pragma unroll
    for (int j = 0; j < 2; j++) acc[i][j] = z4;

  const int KT = K >> 7;
  bf16_t* Ad = lds + wave * 2048;
  bf16_t* Bd = lds + 8192 + wave * 2048;

  for (int kt = 0; kt < KT; kt++) {
    const size_t kb = (size_t)kt * 256;
#pragma unroll
    for (int pp = 0; pp < 4; pp++) {
      g2l16(gA[pp] + kb, Ad + pp * 512);
      g2l16(gB[pp] + kb, Bd + pp * 512);
    }
    __syncthreads();
#pragma unroll
    for (int ks = 0; ks < 4; ks++) {
      bf16x8 af[2], bfr[2];
#pragma unroll
      for (int i = 0; i < 2; i++) {
        int ra = wm + i * 16 + l15;
        af[i] = *(const bf16x8*)(lds + ra * 128 +
                                 (((ks * 4 + quad) ^ (ra & 7)) << 3));
        int rb = wn + i * 16 + l15;
        bfr[i] = *(const bf16x8*)(lds + 8192 + rb * 128 +
                                  (((ks * 4 + quad) ^ (rb & 7)) << 3));
      }
#pragma unroll
      for (int i = 0; i < 2; i++)
#pragma unroll
        for (int j = 0; j < 2; j++) acc[i][j] = MFMA(af[i], bfr[j], acc[i][j]);
    }
    __syncthreads();
  }

  float* s4 = (float*)lds + wave * 1024;
#pragma unroll
  for (int i = 0; i < 2; i++)
#pragma unroll
    for (int j = 0; j < 2; j++)
#pragma unroll
      for (int reg = 0; reg < 4; reg++)
        s4[(i * 16 + quad * 4 + reg) * 32 + j * 16 + l15] = acc[i][j][reg];
  __syncthreads();
#pragma unroll
  for (int pp = 0; pp < 4; pp++) {
    int row = pp * 8 + (lane >> 3);
    int c4 = (lane & 7) * 4;
    floatx4 v = *(const floatx4*)&s4[row * 32 + c4];
    size_t goff = (size_t)(m0 + wm + row) * N + n0 + wn + c4;
    floatx4 rv = *(const floatx4*)(resid + goff);
    floatx4 bv = *(const floatx4*)(bias + n0 + wn + c4);
    *(floatx4*)(outF + goff) = v + rv + bv;
  }
}

// ---------------------------------------------------------------------------
// Flash v6: barrier-free wave-private pipeline, in-register softmax,
// V in registers, K 4-deep LDS, pair-sized iterations.
// Block 256 thr / 4 waves; grid (32 qtiles, 24 bh).  kv-tile 64; wave w owns
// s-slice [kv*64 + w*16, +16).  Per-wave LDS 8 KB: K slots [4][1024]
// (xor-swizzled via pre-swizzled g2l source).  V loads straight to VGPRs
// (per-lane contiguous 16B).  16 pair-iterations; per pair: issue next
// pair's K(4 g2l)+V(4 loads), one s_waitcnt vmcnt(8) drains current pair ->
// slack = full pair body.  No __syncthreads until epilogue.
// ---------------------------------------------------------------------------
__global__ __launch_bounds__(256, 3) void k_flash(
    const bf16_t* __restrict__ qh, const bf16_t* __restrict__ kh,
    const bf16_t* __restrict__ vt, const float* __restrict__ ab,
    bf16_t* __restrict__ attnA) {
  __shared__ bf16_t sm[16896];  // 4 waves x K[4][1024] + 1KB l_red (fp32[4][64])

  const int tid = threadIdx.x, lane = tid & 63, wave = tid >> 6;
  const int quad = lane >> 4, l15 = lane & 15;
  const int qtile = blockIdx.x, bh = blockIdx.y;
  const int h = bh % 12, bq = bh / 12;
  const int myv = qtile >> 1;

  bf16_t* wb = sm + wave * 4096;  // K slots [4][1024]

  const bf16_t* Qg = qh + ((size_t)bh * 2048 + qtile * 64) * 64;
  const bf16_t* Kg = kh + ((size_t)bh * 2048 + wave * 16) * 64;

  // K DMA sources: instr i (0,1): lane -> row s=i*8+(lane>>3), chunk lane&7,
  // source chunk xor-swizzled by (s&7).  Advance 8192 B per kv.
  const char* gK[2];
#pragma unroll
  for (int i = 0; i < 2; i++) {
    int sl = i * 8 + (lane >> 3);
    int cs = (lane & 7) ^ (sl & 7);
    gK[i] = (const char*)(Kg + sl * 64 + cs * 8);
  }

  // V register-load offsets (elems): lane needs V[s=quad*8+j][d=nt*16+l15]
  // = vt[(bh*64+nt*16+l15)*2048 + pair*128 + w*16 + (quad>>1)*64 + (quad&1)*8 + j]
  int voff[4];
#pragma unroll
  for (int nt = 0; nt < 4; nt++)
    voff[nt] = (bh * 64 + nt * 16 + l15) * 2048 + wave * 16 +
               (quad >> 1) * 64 + (quad & 1) * 8;

  // Q in registers: frag per (mt, ks); identical lane map as A or B operand.
  bf16x8 qf[4][2];
#pragma unroll
  for (int mt = 0; mt < 4; mt++)
#pragma unroll
    for (int ks = 0; ks < 2; ks++)
      qf[mt][ks] = *(const bf16x8*)(Qg + (size_t)(mt * 16 + l15) * 64 +
                                    ks * 32 + quad * 8);

  // K-frag read offsets (slot-relative): row l15, chunk swizzled
  int offKr[2];
#pragma unroll
  for (int ks = 0; ks < 2; ks++)
    offKr[ks] = l15 * 64 + ((((ks << 2) + quad) ^ (l15 & 7)) << 3);

  const floatx4 z4 = {0.f, 0.f, 0.f, 0.f};
  floatx4 oacc[4][4];
  float l_mt[4];
  unsigned pA[4], pB[4];
#pragma unroll
  for (int mt = 0; mt < 4; mt++)
#pragma unroll
    for (int nt = 0; nt < 4; nt++) oacc[mt][nt] = z4;
#pragma unroll
  for (int mt = 0; mt < 4; mt++) l_mt[mt] = 0.f;

  const float bc_same = ab[h * 2] * LOG2E;
  const float bc_diff = ab[h * 2 + 1] * LOG2E;
  const float ratio = fexp2(bc_same - bc_diff);
  const floatx4 bD4 = {bc_diff, bc_diff, bc_diff, bc_diff};

  // prologue: K(kv 0,1) -> slots 0,1; V pair 0 -> vfA.  (8 vmem in flight)
  g2l16(gK[0], wb);
  g2l16(gK[1], wb + 512);
  g2l16(gK[0] + 8192, wb + 1024);
  g2l16(gK[1] + 8192, wb + 1024 + 512);
  bf16x8 vfA[4], vfB[4];
#pragma unroll
  for (int nt = 0; nt < 4; nt++) vfA[nt] = *(const bf16x8*)(vt + voff[nt]);

  // Per-pair body: issue pair PJ+1 (4 K g2l + 4 V reg loads), drain pair PJ
  // with vmcnt(8), then S/softmax for both kv and PV with VCUR.
#define PAIR_BODY(PJ, VCUR, VNEXT)                                           \
  {                                                                          \
    const int kve = 2 * (PJ), kvo = kve + 1;                                 \
    const int kn0 = (kve + 2) & 31, kn1 = (kvo + 2) & 31;                    \
    g2l16(gK[0] + (size_t)kn0 * 8192, wb + (kn0 & 3) * 1024);                \
    g2l16(gK[1] + (size_t)kn0 * 8192, wb + (kn0 & 3) * 1024 + 512);          \
    g2l16(gK[0] + (size_t)kn1 * 8192, wb + (kn1 & 3) * 1024);                \
    g2l16(gK[1] + (size_t)kn1 * 8192, wb + (kn1 & 3) * 1024 + 512);          \
    const int vadd = (((PJ) + 1) & 15) * 128;                                \
    _Pragma("unroll")                                                        \
    for (int nt = 0; nt < 4; nt++)                                           \
      VNEXT[nt] = *(const bf16x8*)(vt + voff[nt] + vadd);                    \
    wait_vm8();                                                              \
    const bool same = ((PJ) == myv);                                         \
    {  /* even kv: S-MFMA + exp2 -> pA/pB */                                 \
      const bf16_t* Kc = wb + (kve & 3) * 1024;                              \
      const bf16x8 kf0 = *(const bf16x8*)(Kc + offKr[0]);                    \
      const bf16x8 kf1 = *(const bf16x8*)(Kc + offKr[1]);                    \
      floatx4 se[4];                                                         \
      _Pragma("unroll")                                                      \
      for (int mt = 0; mt < 4; mt++) {                                       \
        se[mt] = MFMA(kf0, qf[mt][0], bD4);                                  \
        se[mt] = MFMA(kf1, qf[mt][1], se[mt]);                               \
      }                                                                      \
      _Pragma("unroll")                                                      \
      for (int mt = 0; mt < 4; mt++) {                                       \
        float p0 = fexp2(se[mt][0]), p1 = fexp2(se[mt][1]);                  \
        float p2 = fexp2(se[mt][2]), p3 = fexp2(se[mt][3]);                  \
        if (same) { p0 *= ratio; p1 *= ratio; p2 *= ratio; p3 *= ratio; }    \
        l_mt[mt] += (p0 + p1) + (p2 + p3);                                   \
        pA[mt] = cvt_pk_bf16(p0, p1);                                        \
        pB[mt] = cvt_pk_bf16(p2, p3);                                        \
      }                                                                      \
    }                                                                        \
    {  /* odd kv: S-MFMA + exp2 + permlane transpose + PV */                 \
      const bf16_t* Kc = wb + (kvo & 3) * 1024;                              \
      const bf16x8 kf0 = *(const bf16x8*)(Kc + offKr[0]);                    \
      const bf16x8 kf1 = *(const bf16x8*)(Kc + offKr[1]);                    \
      floatx4 so[4];                                                         \
      _Pragma("unroll")                                                      \
      for (int mt = 0; mt < 4; mt++) {                                       \
        so[mt] = MFMA(kf0, qf[mt][0], bD4);                                  \
        so[mt] = MFMA(kf1, qf[mt][1], so[mt]);                               \
      }                                                                      \
      _Pragma("unroll")                                                      \
      for (int mt = 0; mt < 4; mt++) {                                       \
        float p0 = fexp2(so[mt][0]), p1 = fexp2(so[mt][1]);                  \
        float p2 = fexp2(so[mt][2]), p3 = fexp2(so[mt][3]);                  \
        if (same) { p0 *= ratio; p1 *= ratio; p2 *= ratio; p3 *= ratio; }    \
        l_mt[mt] += (p0 + p1) + (p2 + p3);                                   \
        unsigned b0 = cvt_pk_bf16(p0, p1);                                   \
        unsigned b1 = cvt_pk_bf16(p2, p3);                                   \
        unsigned a0 = pA[mt], a1 = pB[mt];                                   \
        pl32swap(a0, b0);                                                    \
        pl16swap(a0, b0);                                                    \
        pl32swap(a1, b1);                                                    \
        pl16swap(a1, b1);                                                    \
        u32x4 wr;                                                            \
        wr[0] = a0; wr[1] = a1; wr[2] = b0; wr[3] = b1;                      \
        const bf16x8 pf = __builtin_bit_cast(bf16x8, wr);                    \
        _Pragma("unroll")                                                    \
        for (int nt = 0; nt < 4; nt++)                                       \
          oacc[mt][nt] = MFMA(pf, VCUR[nt], oacc[mt][nt]);                   \
      }                                                                      \
    }                                                                        \
  }

  for (int pj = 0; pj < 16; pj += 2) {
    PAIR_BODY(pj, vfA, vfB);
    PAIR_BODY(pj + 1, vfB, vfA);
  }
#undef PAIR_BODY

  wait_vm0();  // drain wraparound prefetch before epilogue reuses K LDS

  // ---- epilogue: cross-wave l and O reduction ----
#pragma unroll
  for (int mt = 0; mt < 4; mt++) {
    float v = l_mt[mt];
    v += __shfl_xor(v, 16);
    v += __shfl_xor(v, 32);
    l_mt[mt] = v;
  }
  float* lred = (float*)(sm + 16384);  // [4][64]
  if (quad == 0) {
#pragma unroll
    for (int mt = 0; mt < 4; mt++)
      lred[wave * 64 + mt * 16 + l15] = l_mt[mt];
  }
  // partial O (bf16) into wave's own K region [64][64]
#pragma unroll
  for (int mt = 0; mt < 4; mt++)
#pragma unroll
    for (int nt = 0; nt < 4; nt++)
#pragma unroll
      for (int reg = 0; reg < 4; reg++)
        wb[(mt * 16 + quad * 4 + reg) * 64 + nt * 16 + l15] =
            f2bf(oacc[mt][nt][reg]);
  __syncthreads();

  const int q = tid >> 2, dg = (tid & 3) * 16;
  const float inv =
      1.0f / (lred[q] + lred[64 + q] + lred[128 + q] + lred[192 + q]);
  float o[16];
#pragma unroll
  for (int j = 0; j < 16; j++) o[j] = 0.f;
#pragma unroll
  for (int w = 0; w < 4; w++) {
    const bf16x8 a = *(const bf16x8*)(sm + w * 4096 + q * 64 + dg);
    const bf16x8 b = *(const bf16x8*)(sm + w * 4096 + q * 64 + dg + 8);
#pragma unroll
    for (int j = 0; j < 8; j++) {
      o[j] += (float)a[j];
      o[8 + j] += (float)b[j];
    }
  }
  bf16x8 r0, r1;
#pragma unroll
  for (int j = 0; j < 8; j++) {
    r0[j] = f2bf(o[j] * inv);
    r1[j] = f2bf(o[8 + j] * inv);
  }
  bf16_t* outp =
      attnA + ((size_t)(bq * 2048 + qtile * 64 + q)) * 768 + h * 64 + dg;
  *(bf16x8*)outp = r0;
  *(bf16x8*)(outp + 8) = r1;
}

// ---------------------------------------------------------------------------
extern "C" void kernel_launch(void* const* d_in, const int* in_sizes, int n_in,
                              void* d_out, int out_size, void* d_ws,
                              size_t ws_size, hipStream_t stream) {
  const float* hs  = (const float*)d_in[0];
  const float* wq  = (const float*)d_in[1];
  const float* bq  = (const float*)d_in[2];
  const float* wk  = (const float*)d_in[3];
  const float* bk  = (const float*)d_in[4];
  const float* wv  = (const float*)d_in[5];
  const float* bv  = (const float*)d_in[6];
  const float* wo  = (const float*)d_in[7];
  const float* bo  = (const float*)d_in[8];
  const float* ab  = (const float*)d_in[9];
  const float* g1  = (const float*)d_in[10];
  const float* be1 = (const float*)d_in[11];
  const float* g3  = (const float*)d_in[12];
  const float* be3 = (const float*)d_in[13];
  const float* w1  = (const float*)d_in[14];
  const float* b1  = (const float*)d_in[15];
  const float* w2  = (const float*)d_in[16];
  const float* b2  = (const float*)d_in[17];

  char* ws = (char*)d_ws;
  size_t off = 0;
  auto alloc = [&](size_t bytes) -> void* {
    void* p = ws + off;
    off += (bytes + 255) & ~(size_t)255;
    return p;
  };
  bf16_t* wqkvT = (bf16_t*)alloc((size_t)2304 * 768 * 2);
  bf16_t* woT   = (bf16_t*)alloc((size_t)768 * 768 * 2);
  bf16_t* w1T   = (bf16_t*)alloc((size_t)3072 * 768 * 2);
  bf16_t* w2T   = (bf16_t*)alloc((size_t)768 * 3072 * 2);
  bf16_t* ni    = (bf16_t*)alloc((size_t)4096 * 768 * 2);
  bf16_t* qhB   = (bf16_t*)alloc((size_t)24 * 2048 * 64 * 2);
  bf16_t* khB   = (bf16_t*)alloc((size_t)24 * 2048 * 64 * 2);
  bf16_t* vtB   = (bf16_t*)alloc((size_t)24 * 64 * 2048 * 2);
  bf16_t* attnA = (bf16_t*)alloc((size_t)4096 * 768 * 2);
  float*  resid1 = (float*)alloc((size_t)4096 * 768 * 4);
  bf16_t* ffn1o = qhB;  // overlay: q/k/v/attn region dead by FFN1 time

  // prep: all transposes + LN1, one dispatch
  PrepP pp = {wq, wk, wv, wo, w1, w2, wqkvT, woT, w1T, w2T, hs, g1, be1, ni};
  k_prep<<<11008, 256, 0, stream>>>(pp);

  // QKV (fused, N=2304): bias, q*0.125*log2e, p-RoPE, head-layout scatter
  GemmP gqkv = {ni, wqkvT, 4096, 2304, 768, 0,
                bq, bk, bv, nullptr, qhB, khB, vtB};
  k_gemm<<<dim3(18, 32), 256, 0, stream>>>(gqkv);

  // flash attention v6 (V-in-registers, K 4-deep, pair pipeline)
  k_flash<<<dim3(32, 24), 256, 0, stream>>>(qhB, khB, vtB, ab, attnA);

  // attn @ wo + bo + residual(hidden) -> resid1 (fp32)
  k_gemm64<<<dim3(12, 64), 256, 0, stream>>>(attnA, woT, 768, 768, bo, hs,
                                             resid1);

  // LN3
  k_layernorm<<<4096, 256, 0, stream>>>(resid1, g3, be3, ni);

  // FFN1 + exact GELU -> bf16
  GemmP gf1 = {ni, w1T, 4096, 3072, 768, 2,
               b1, nullptr, nullptr, nullptr, ffn1o, nullptr, nullptr};
  k_gemm<<<dim3(24, 32), 256, 0, stream>>>(gf1);

  // FFN2 + b2 + residual -> d_out (fp32 [4096][768])
  k_gemm64<<<dim3(12, 64), 256, 0, stream>>>(ffn1o, w2T, 768, 3072, b2,
                                             resid1, (float*)d_out);
}

// Round 5
// 264.443 us; speedup vs baseline: 1.2629x; 1.2629x over previous
//
#include <hip/hip_runtime.h>
#include <cmath>

// ---------------------------------------------------------------------------
// PatchTST encoder layer w/ p-RoPE, MI355X (gfx950).  Round 12:
//  - GEMMs/prep/LN unchanged.
//  - flash v7: v5 (in-register softmax + native exp2 + bias-in-C-in, all
//    g2l-coalesced K/V) + DEEPER LDS RINGS, same footprint:
//    K 3-slot ring (2-iter prefetch slack), V 3-slot ring (1-iter slack,
//    consumed late in the odd body).  Per iter: issue V(kv+1) then K(kv+2),
//    one s_waitcnt vmcnt(6) drains exactly K(kv)+V(kv) while K(kv+1) flies.
//    Slot indices = wave-uniform SGPR rotation (sa,sb,sc) - zero VGPR cost.
//    (v6 post-mortem: V-to-registers + 2-pair unroll spilled ~26 regs ->
//    140 MB scratch writes; and per-lane V scatter 2x-overfetched.  Reverted
//    to coalesced g2l; depth now lives in LDS, not VGPRs.)
// Fragment layouts (verified, guide §3, 16x16x32 only):
//   A[m=lane&15][k=quad*8+j]; B[k=quad*8+j][n=lane&15];
//   C/D col=lane&15, row=quad*4+reg.   (A and B lane maps are identical, so
//   swapping MFMA operands transposes C with no fragment-read change.)
// ---------------------------------------------------------------------------

typedef __bf16 bf16_t;
typedef bf16_t bf16x8 __attribute__((ext_vector_type(8)));
typedef float floatx4 __attribute__((ext_vector_type(4)));
typedef unsigned int u32x4 __attribute__((ext_vector_type(4)));

#define MFMA(a, b, c) __builtin_amdgcn_mfma_f32_16x16x32_bf16((a), (b), (c), 0, 0, 0)
#define LOG2E 1.44269504088896340736f

__device__ __forceinline__ bf16_t f2bf(float f) { return (bf16_t)f; }

__device__ __forceinline__ float fexp2(float x) {
  return __builtin_amdgcn_exp2f(x);  // raw v_exp_f32
}

__device__ __forceinline__ void g2l16(const void* g, void* l) {
  __builtin_amdgcn_global_load_lds(
      (const __attribute__((address_space(1))) unsigned int*)g,
      (__attribute__((address_space(3))) unsigned int*)l, 16, 0, 0);
}

__device__ __forceinline__ void wait_vm6() {
  asm volatile("s_waitcnt vmcnt(6)" ::: "memory");
}
__device__ __forceinline__ void wait_vm0() {
  asm volatile("s_waitcnt vmcnt(0)" ::: "memory");
}

// pack two f32 -> bf16x2 (lo = first operand)
__device__ __forceinline__ unsigned cvt_pk_bf16(float lo, float hi) {
  unsigned r;
  asm("v_cvt_pk_bf16_f32 %0, %1, %2" : "=v"(r) : "v"(lo), "v"(hi));
  return r;
}
// swap rows(16-lane groups): a.row{2,3} <-> b.row{0,1}
__device__ __forceinline__ void pl32swap(unsigned& a, unsigned& b) {
  asm("v_permlane32_swap_b32 %0, %1" : "+v"(a), "+v"(b));
}
// swap a.row{1,3} <-> b.row{0,2}
__device__ __forceinline__ void pl16swap(unsigned& a, unsigned& b) {
  asm("v_permlane16_swap_b32 %0, %1" : "+v"(a), "+v"(b));
}

// ---------------------------------------------------------------------------
// k_prep: all weight transposes (fp32 [R][C] -> bf16 [C][R]) + LN1, one grid.
// ---------------------------------------------------------------------------
struct PrepP {
  const float *wq, *wk, *wv, *wo, *w1, *w2;
  bf16_t *wqkvT, *woT, *w1T, *w2T;
  const float *hs, *g1, *be1;
  bf16_t* ni;
};

__global__ __launch_bounds__(256) void k_prep(PrepP p) {
  __shared__ float shm[32 * 33];
  const int bid = blockIdx.x;
  if (bid < 6912) {
    const float* in;
    bf16_t* out;
    int R, C, tx, ty;
    if (bid < 2304) {
      int m = bid / 576, lo = bid % 576;
      in = (m == 0) ? p.wq : (m == 1) ? p.wk : (m == 2) ? p.wv : p.wo;
      out = (m < 3) ? p.wqkvT + (size_t)m * 768 * 768 : p.woT;
      R = 768; C = 768; tx = lo % 24; ty = lo / 24;
    } else if (bid < 4608) {
      int lo = bid - 2304;
      in = p.w1; out = p.w1T; R = 768; C = 3072; tx = lo % 96; ty = lo / 96;
    } else {
      int lo = bid - 4608;
      in = p.w2; out = p.w2T; R = 3072; C = 768; tx = lo % 24; ty = lo / 24;
    }
    const int c0 = tx * 32, r0 = ty * 32;
    const int lx = threadIdx.x & 31, ly = threadIdx.x >> 5;
#pragma unroll
    for (int p4 = 0; p4 < 4; p4++) {
      int r = ly + p4 * 8;
      shm[r * 33 + lx] = in[(size_t)(r0 + r) * C + c0 + lx];
    }
    __syncthreads();
#pragma unroll
    for (int p4 = 0; p4 < 4; p4++) {
      int r = ly + p4 * 8;
      out[(size_t)(c0 + r) * R + r0 + lx] = f2bf(shm[lx * 33 + r]);
    }
  } else {
    const int row = bid - 6912;
    const float* xr = p.hs + (size_t)row * 768;
    const int t = threadIdx.x;
    float v0 = xr[t], v1 = xr[t + 256], v2 = xr[t + 512];
    float s = v0 + v1 + v2;
    float s2 = v0 * v0 + v1 * v1 + v2 * v2;
#pragma unroll
    for (int off = 32; off; off >>= 1) {
      s += __shfl_xor(s, off);
      s2 += __shfl_xor(s2, off);
    }
    const int w = t >> 6;
    if ((t & 63) == 0) { shm[w] = s; shm[4 + w] = s2; }
    __syncthreads();
    s = shm[0] + shm[1] + shm[2] + shm[3];
    s2 = shm[4] + shm[5] + shm[6] + shm[7];
    const float mu = s * (1.0f / 768.0f);
    const float var = s2 * (1.0f / 768.0f) - mu * mu;
    const float rstd = rsqrtf(var + 1e-5f);
    bf16_t* orow = p.ni + (size_t)row * 768;
    orow[t]       = f2bf((v0 - mu) * rstd * p.g1[t]       + p.be1[t]);
    orow[t + 256] = f2bf((v1 - mu) * rstd * p.g1[t + 256] + p.be1[t + 256]);
    orow[t + 512] = f2bf((v2 - mu) * rstd * p.g1[t + 512] + p.be1[t + 512]);
  }
}

// ---------------------------------------------------------------------------
// LayerNorm (LN3): fp32 in -> bf16 out, one block per row.
// ---------------------------------------------------------------------------
__global__ __launch_bounds__(256) void k_layernorm(
    const float* __restrict__ x, const float* __restrict__ g,
    const float* __restrict__ b, bf16_t* __restrict__ out) {
  const int row = blockIdx.x;
  const float* xr = x + (size_t)row * 768;
  const int t = threadIdx.x;
  float v0 = xr[t], v1 = xr[t + 256], v2 = xr[t + 512];
  float s = v0 + v1 + v2;
  float s2 = v0 * v0 + v1 * v1 + v2 * v2;
#pragma unroll
  for (int off = 32; off; off >>= 1) {
    s += __shfl_xor(s, off);
    s2 += __shfl_xor(s2, off);
  }
  __shared__ float ra[4], rb[4];
  const int w = t >> 6;
  if ((t & 63) == 0) { ra[w] = s; rb[w] = s2; }
  __syncthreads();
  s = ra[0] + ra[1] + ra[2] + ra[3];
  s2 = rb[0] + rb[1] + rb[2] + rb[3];
  const float mu = s * (1.0f / 768.0f);
  const float var = s2 * (1.0f / 768.0f) - mu * mu;
  const float rstd = rsqrtf(var + 1e-5f);
  bf16_t* orow = out + (size_t)row * 768;
  orow[t]       = f2bf((v0 - mu) * rstd * g[t]       + b[t]);
  orow[t + 256] = f2bf((v1 - mu) * rstd * g[t + 256] + b[t + 256]);
  orow[t + 512] = f2bf((v2 - mu) * rstd * g[t + 512] + b[t + 512]);
}

// ---------------------------------------------------------------------------
// 128x128-tile bf16 MFMA GEMM (QKV mode 0, FFN1 mode 2). m97 structure (r5).
// ---------------------------------------------------------------------------
struct GemmP {
  const bf16_t* A;
  const bf16_t* Bt;
  int M, N, K, mode;
  const float* bias0;
  const float* bias1;
  const float* bias2;
  float* outF;
  bf16_t* outB0;
  bf16_t* outB1;
  bf16_t* outB2;
};

__global__ __launch_bounds__(256, 3) void k_gemm(GemmP p) {
  __shared__ bf16_t lds[18432];  // 36 KiB
  const int tid = threadIdx.x;
  const int lane = tid & 63, wave = tid >> 6;
  const int quad = lane >> 4, l15 = lane & 15;
  const int wm = (wave >> 1) * 64, wn = (wave & 1) * 64;
  const int m0 = blockIdx.y * 128, n0 = blockIdx.x * 128;

  const char* gA[4];
  const char* gB[4];
#pragma unroll
  for (int pp = 0; pp < 4; pp++) {
    int slot = wave * 256 + pp * 64 + lane;
    int r = slot >> 3;
    int c8 = ((slot & 7) ^ (r & 7)) << 3;
    gA[pp] = (const char*)(p.A + (size_t)(m0 + r) * p.K + c8);
    gB[pp] = (const char*)(p.Bt + (size_t)(n0 + r) * p.K + c8);
  }

  int offA[4], offB[4];
#pragma unroll
  for (int i = 0; i < 4; i++) {
    int ra = wm + i * 16 + l15;
    offA[i] = ra * 64 + ((quad * 8) ^ ((ra & 7) << 3));
    int rb = wn + i * 16 + l15;
    offB[i] = rb * 64 + ((quad * 8) ^ ((rb & 7) << 3));
  }

  const floatx4 z4 = {0.f, 0.f, 0.f, 0.f};
  floatx4 acc[4][4];
#pragma unroll
  for (int i = 0; i < 4; i++)
#pragma unroll
    for (int j = 0; j < 4; j++) acc[i][j] = z4;

  const int KT = p.K >> 6;
  bf16_t* Ad = lds + wave * 2048;
  bf16_t* Bd = lds + 8192 + wave * 2048;

  for (int kt = 0; kt < KT; kt++) {
    const size_t kb = (size_t)kt * 128;
#pragma unroll
    for (int pp = 0; pp < 4; pp++) {
      g2l16(gA[pp] + kb, Ad + pp * 512);
      g2l16(gB[pp] + kb, Bd + pp * 512);
    }
    __syncthreads();
#pragma unroll
    for (int ks = 0; ks < 2; ks++) {
      bf16x8 af[4], bfr[4];
#pragma unroll
      for (int i = 0; i < 4; i++) {
        af[i] = *(const bf16x8*)(lds + (offA[i] ^ (ks * 32)));
        bfr[i] = *(const bf16x8*)(lds + 8192 + (offB[i] ^ (ks * 32)));
      }
#pragma unroll
      for (int i = 0; i < 4; i++)
#pragma unroll
        for (int j = 0; j < 4; j++) acc[i][j] = MFMA(af[i], bfr[j], acc[i][j]);
    }
    __syncthreads();
  }

  char* scr = (char*)lds + wave * 9216;

  if (p.mode == 0) {
    const int gnw = n0 + wn;
    const int region = gnw / 768;  // block-uniform
    const int rem = gnw - region * 768;
    const int h = rem >> 6;
    const int b = (m0 + wm) >> 11;
    const int t0 = (m0 + wm) & 2047;
    const float* bias = (region == 0) ? p.bias0 : (region == 1 ? p.bias1 : p.bias2);
    float bb[4];
#pragma unroll
    for (int j = 0; j < 4; j++) bb[j] = bias[h * 64 + j * 16 + l15];
    bf16_t* sb = (bf16_t*)scr;  // [64][72]
    if (region < 2) {
      const float scale = (region == 0) ? 0.125f * LOG2E : 1.0f;
      const float inv_ts = exp2f(-(float)l15 * (13.287712379549449f / 32.0f));
#pragma unroll
      for (int i = 0; i < 4; i++) {
#pragma unroll
        for (int reg = 0; reg < 4; reg++) {
          int tl = i * 16 + quad * 4 + reg;
          float sn, cs;
          __sincosf((float)(t0 + tl) * inv_ts, &sn, &cs);
          float v0 = (acc[i][0][reg] + bb[0]) * scale;
          float v1 = (acc[i][1][reg] + bb[1]) * scale;
          float v2 = (acc[i][2][reg] + bb[2]) * scale;
          float v3 = (acc[i][3][reg] + bb[3]) * scale;
          sb[tl * 72 + l15]      = f2bf(v0 * cs - v2 * sn);
          sb[tl * 72 + 16 + l15] = f2bf(v1);
          sb[tl * 72 + 32 + l15] = f2bf(v2 * cs + v0 * sn);
          sb[tl * 72 + 48 + l15] = f2bf(v3);
        }
      }
      __syncthreads();
      bf16_t* outp = (region == 0) ? p.outB0 : p.outB1;
      bf16_t* ob = outp + (((size_t)(b * 12 + h) * 2048 + t0) << 6);
#pragma unroll
      for (int pp = 0; pp < 8; pp++) {
        int row = pp * 8 + (lane >> 3), ch = (lane & 7) << 3;
        *(bf16x8*)(ob + row * 64 + ch) = *(const bf16x8*)&sb[row * 72 + ch];
      }
    } else {
#pragma unroll
      for (int i = 0; i < 4; i++)
#pragma unroll
        for (int j = 0; j < 4; j++)
#pragma unroll
          for (int reg = 0; reg < 4; reg++)
            sb[(j * 16 + l15) * 72 + i * 16 + quad * 4 + reg] =
                f2bf(acc[i][j][reg] + bb[j]);
      __syncthreads();
      bf16_t* ob = p.outB2 + (((size_t)(b * 12 + h)) << 17) + t0;
#pragma unroll
      for (int pp = 0; pp < 8; pp++) {
        int d = pp * 8 + (lane >> 3), ch = (lane & 7) << 3;
        *(bf16x8*)(ob + (size_t)d * 2048 + ch) = *(const bf16x8*)&sb[d * 72 + ch];
      }
    }
  } else {  // mode 2: FFN1 + exact GELU -> bf16
    bf16_t* sb = (bf16_t*)scr;  // [64][72]
    float bb[4];
#pragma unroll
    for (int j = 0; j < 4; j++) bb[j] = p.bias0[n0 + wn + j * 16 + l15];
#pragma unroll
    for (int i = 0; i < 4; i++)
#pragma unroll
      for (int j = 0; j < 4; j++)
#pragma unroll
        for (int reg = 0; reg < 4; reg++) {
          int tl = i * 16 + quad * 4 + reg;
          float x = acc[i][j][reg] + bb[j];
          float gv = 0.5f * x * (1.0f + erff(x * 0.70710678118654752f));
          sb[tl * 72 + j * 16 + l15] = f2bf(gv);
        }
    __syncthreads();
#pragma unroll
    for (int pp = 0; pp < 8; pp++) {
      int row = pp * 8 + (lane >> 3), ch = (lane & 7) << 3;
      *(bf16x8*)(p.outB0 + (size_t)(m0 + wm + row) * p.N + n0 + wn + ch) =
          *(const bf16x8*)&sb[row * 72 + ch];
    }
  }
}

// ---------------------------------------------------------------------------
// 64x64-tile GEMM (WO, FFN2): fp32 out = acc + bias + resid.  (r5 version)
// ---------------------------------------------------------------------------
__global__ __launch_bounds__(256, 4) void k_gemm64(
    const bf16_t* __restrict__ A, const bf16_t* __restrict__ Bt, int N, int K,
    const float* __restrict__ bias, const float* __restrict__ resid,
    float* __restrict__ outF) {
  __shared__ bf16_t lds[16384];  // 32 KiB
  const int tid = threadIdx.x;
  const int lane = tid & 63, wave = tid >> 6;
  const int quad = lane >> 4, l15 = lane & 15;
  const int wm = (wave >> 1) * 32, wn = (wave & 1) * 32;
  const int m0 = blockIdx.y * 64, n0 = blockIdx.x * 64;

  const char* gA[4];
  const char* gB[4];
#pragma unroll
  for (int pp = 0; pp < 4; pp++) {
    int slot = wave * 256 + pp * 64 + lane;
    int r = slot >> 4;
    int c = ((slot & 15) ^ (r & 7)) << 3;  // elems
    gA[pp] = (const char*)(A + (size_t)(m0 + r) * K + c);
    gB[pp] = (const char*)(Bt + (size_t)(n0 + r) * K + c);
  }

  const floatx4 z4 = {0.f, 0.f, 0.f, 0.f};
  floatx4 acc[2][2];
#pragma unroll
  for (int i = 0; i < 2; i++)
#pragma unroll
    for (int j = 0; j < 2; j++) acc[i][j] = z4;

  const int KT = K >> 7;
  bf16_t* Ad = lds + wave * 2048;
  bf16_t* Bd = lds + 8192 + wave * 2048;

  for (int kt = 0; kt < KT; kt++) {
    const size_t kb = (size_t)kt * 256;
#pragma unroll
    for (int pp = 0; pp < 4; pp++) {
      g2l16(gA[pp] + kb, Ad + pp * 512);
      g2l16(gB[pp] + kb, Bd + pp * 512);
    }
    __syncthreads();
#pragma unroll
    for (int ks = 0; ks < 4; ks++) {
      bf16x8 af[2], bfr[2];
#pragma unroll
      for (int i = 0; i < 2; i++) {
        int ra = wm + i * 16 + l15;
        af[i] = *(const bf16x8*)(lds + ra * 128 +
                                 (((ks * 4 + quad) ^ (ra & 7)) << 3));
        int rb = wn + i * 16 + l15;
        bfr[i] = *(const bf16x8*)(lds + 8192 + rb * 128 +
                                  (((ks * 4 + quad) ^ (rb & 7)) << 3));
      }
#pragma unroll
      for (int i = 0; i < 2; i++)
#pragma unroll
        for (int j = 0; j < 2; j++) acc[i][j] = MFMA(af[i], bfr[j], acc[i][j]);
    }
    __syncthreads();
  }

  float* s4 = (float*)lds + wave * 1024;
#pragma unroll
  for (int i = 0; i < 2; i++)
#pragma unroll
    for (int j = 0; j < 2; j++)
#pragma unroll
      for (int reg = 0; reg < 4; reg++)
        s4[(i * 16 + quad * 4 + reg) * 32 + j * 16 + l15] = acc[i][j][reg];
  __syncthreads();
#pragma unroll
  for (int pp = 0; pp < 4; pp++) {
    int row = pp * 8 + (lane >> 3);
    int c4 = (lane & 7) * 4;
    floatx4 v = *(const floatx4*)&s4[row * 32 + c4];
    size_t goff = (size_t)(m0 + wm + row) * N + n0 + wn + c4;
    floatx4 rv = *(const floatx4*)(resid + goff);
    floatx4 bv = *(const floatx4*)(bias + n0 + wn + c4);
    *(floatx4*)(outF + goff) = v + rv + bv;
  }
}

// ---------------------------------------------------------------------------
// Flash v7: barrier-free wave-private pipeline, in-register softmax,
// K 3-ring (2-iter slack) + V 3-ring (1-iter slack), all g2l-coalesced.
// Block 256 thr / 4 waves; grid (32 qtiles, 24 bh).  kv-tile 64; wave w owns
// s-slice [kv*64 + w*16, +16).  Per-wave LDS 12 KB: K[3][1024] + V[3][1024].
// Per iter: issue V(kv+1)->slot sb, K(kv+2)->slot sc, s_waitcnt vmcnt(6)
// (drains K(kv)+V(kv), K(kv+1) stays in flight).  (sa,sb,sc) = wave-uniform
// SGPR rotation of (kv, kv+1, kv+2) mod 3.  No __syncthreads until epilogue.
// ---------------------------------------------------------------------------
__global__ __launch_bounds__(256, 3) void k_flash(
    const bf16_t* __restrict__ qh, const bf16_t* __restrict__ kh,
    const bf16_t* __restrict__ vt, const float* __restrict__ ab,
    bf16_t* __restrict__ attnA) {
  __shared__ bf16_t sm[25088];  // 4 x 6144 (K ring + V ring) + 512 (l_red fp32[4][64])

  const int tid = threadIdx.x, lane = tid & 63, wave = tid >> 6;
  const int quad = lane >> 4, l15 = lane & 15;
  const int qtile = blockIdx.x, bh = blockIdx.y;
  const int h = bh % 12, bq = bh / 12;
  const int myv = qtile >> 1;

  bf16_t* wb = sm + wave * 6144;  // K ring [3][1024]
  bf16_t* Vb = wb + 3072;         // V ring [3][1024]

  const bf16_t* Qg = qh + ((size_t)bh * 2048 + qtile * 64) * 64;
  const bf16_t* Kg = kh + ((size_t)bh * 2048 + wave * 16) * 64;

  // K DMA sources: instr i (0,1): lane -> row s=i*8+(lane>>3), chunk lane&7,
  // source chunk xor-swizzled by (s&7).  Advance 8192 B per kv.
  const char* gK[2];
#pragma unroll
  for (int i = 0; i < 2; i++) {
    int sl = i * 8 + (lane >> 3);
    int cs = (lane & 7) ^ (sl & 7);
    gK[i] = (const char*)(Kg + sl * 64 + cs * 8);
  }
  // V DMA sources: instr i: lane -> d=i*32+(lane>>1), half lane&1, source
  // half xor ((d>>2)&1).  Advance 128 B per kv.
  const char* gV[2];
#pragma unroll
  for (int i = 0; i < 2; i++) {
    int d = i * 32 + (lane >> 1);
    int hs = (lane & 1) ^ ((d >> 2) & 1);
    gV[i] = (const char*)(vt + ((size_t)(bh * 64 + d)) * 2048 + wave * 16 + hs * 8);
  }

  // Q in registers: frag per (mt, ks); identical lane map as A or B operand.
  bf16x8 qf[4][2];
#pragma unroll
  for (int mt = 0; mt < 4; mt++)
#pragma unroll
    for (int ks = 0; ks < 2; ks++)
      qf[mt][ks] = *(const bf16x8*)(Qg + (size_t)(mt * 16 + l15) * 64 +
                                    ks * 32 + quad * 8);

  // K-frag read offsets (slot-relative): row l15, chunk swizzled
  int offKr[2];
#pragma unroll
  for (int ks = 0; ks < 2; ks++)
    offKr[ks] = l15 * 64 + ((((ks << 2) + quad) ^ (l15 & 7)) << 3);
  // V-frag read offsets (slot-relative): d row, swizzled half
  int offV[4];
#pragma unroll
  for (int nt = 0; nt < 4; nt++) {
    int d = nt * 16 + l15;
    offV[nt] = d * 16 + (((quad & 1) ^ ((d >> 2) & 1)) << 3);
  }

  const floatx4 z4 = {0.f, 0.f, 0.f, 0.f};
  floatx4 oacc[4][4];
  float l_mt[4];
  unsigned pA[4], pB[4];
#pragma unroll
  for (int mt = 0; mt < 4; mt++)
#pragma unroll
    for (int nt = 0; nt < 4; nt++) oacc[mt][nt] = z4;
#pragma unroll
  for (int mt = 0; mt < 4; mt++) l_mt[mt] = 0.f;

  const float bc_same = ab[h * 2] * LOG2E;
  const float bc_diff = ab[h * 2 + 1] * LOG2E;
  const float ratio = fexp2(bc_same - bc_diff);
  const floatx4 bD4 = {bc_diff, bc_diff, bc_diff, bc_diff};

  // prologue (6 in flight, oldest->newest): K(0)->slot0, V(0)->Vslot0,
  // K(1)->slot1.  Matches steady-state drain order for vmcnt(6).
  g2l16(gK[0], wb);
  g2l16(gK[1], wb + 512);
  g2l16(gV[0], Vb);
  g2l16(gV[1], Vb + 512);
  g2l16(gK[0] + 8192, wb + 1024);
  g2l16(gK[1] + 8192, wb + 1024 + 512);

  int sa = 0, sb = 1, sc = 2;  // kv%3, (kv+1)%3, (kv+2)%3 (wave-uniform)

#pragma unroll 2
  for (int kv = 0; kv < 32; kv++) {
    // issue V(kv+1) -> V slot sb, then K(kv+2) -> K slot sc
    {
      const size_t kbV = (size_t)((kv + 1) & 31) * 128;
      g2l16(gV[0] + kbV, Vb + sb * 1024);
      g2l16(gV[1] + kbV, Vb + sb * 1024 + 512);
      const size_t kbK = (size_t)((kv + 2) & 31) * 8192;
      g2l16(gK[0] + kbK, wb + sc * 1024);
      g2l16(gK[1] + kbK, wb + sc * 1024 + 512);
    }
    wait_vm6();  // drains K(kv)+V(kv); K(kv+1) keeps flying

    const bf16_t* Kc = wb + sa * 1024;
    // swapped S-MFMA: A=K (m=s), B=Q (n=q); diff-bias preloaded via C-in.
    floatx4 sacc[4];
    {
      const bf16x8 kf0 = *(const bf16x8*)(Kc + offKr[0]);
      const bf16x8 kf1 = *(const bf16x8*)(Kc + offKr[1]);
#pragma unroll
      for (int mt = 0; mt < 4; mt++) {
        sacc[mt] = MFMA(kf0, qf[mt][0], bD4);
        sacc[mt] = MFMA(kf1, qf[mt][1], sacc[mt]);
      }
    }
    // sacc[mt][reg] = S[s = quad*4+reg][q = mt*16+l15]  (+bc_diff)
    const bool same = ((kv >> 1) == myv);  // wave-uniform, 2 of 32 iters

    if (!(kv & 1)) {  // even: exp2 + pack, hold in regs for the pair
#pragma unroll
      for (int mt = 0; mt < 4; mt++) {
        float p0 = fexp2(sacc[mt][0]), p1 = fexp2(sacc[mt][1]);
        float p2 = fexp2(sacc[mt][2]), p3 = fexp2(sacc[mt][3]);
        if (same) { p0 *= ratio; p1 *= ratio; p2 *= ratio; p3 *= ratio; }
        l_mt[mt] += (p0 + p1) + (p2 + p3);
        pA[mt] = cvt_pk_bf16(p0, p1);
        pB[mt] = cvt_pk_bf16(p2, p3);
      }
    } else {  // odd: exp2 + pack, permlane-transpose -> PV over s=32
      // V pair bases: quads 0,1 read V(kv-1) = slot sc; quads 2,3 V(kv) = sa.
      const int vbase = ((quad >> 1) ? sa : sc) * 1024;
      bf16x8 vf[4];
#pragma unroll
      for (int nt = 0; nt < 4; nt++)
        vf[nt] = *(const bf16x8*)(Vb + vbase + offV[nt]);
#pragma unroll
      for (int mt = 0; mt < 4; mt++) {
        float p0 = fexp2(sacc[mt][0]), p1 = fexp2(sacc[mt][1]);
        float p2 = fexp2(sacc[mt][2]), p3 = fexp2(sacc[mt][3]);
        if (same) { p0 *= ratio; p1 *= ratio; p2 *= ratio; p3 *= ratio; }
        l_mt[mt] += (p0 + p1) + (p2 + p3);
        unsigned b0 = cvt_pk_bf16(p0, p1);
        unsigned b1 = cvt_pk_bf16(p2, p3);
        unsigned a0 = pA[mt], a1 = pB[mt];
        // build A-frag words: lane(quad,l15) needs P[q=l15][s=quad*8+j].
        pl32swap(a0, b0);
        pl16swap(a0, b0);  // a0 = word0 (k=0,1), b0 = word2 (k=4,5)
        pl32swap(a1, b1);
        pl16swap(a1, b1);  // a1 = word1 (k=2,3), b1 = word3 (k=6,7)
        u32x4 wr;
        wr[0] = a0; wr[1] = a1; wr[2] = b0; wr[3] = b1;
        const bf16x8 pf = __builtin_bit_cast(bf16x8, wr);
#pragma unroll
        for (int nt = 0; nt < 4; nt++)
          oacc[mt][nt] = MFMA(pf, vf[nt], oacc[mt][nt]);
      }
    }
    // rotate slots: (sa,sb,sc) <- (sb,sc,sa)
    int tmp = sa; sa = sb; sb = sc; sc = tmp;
  }

  wait_vm0();  // drain wraparound prefetch before epilogue reuses LDS

  // ---- epilogue: cross-wave l and O reduction ----
#pragma unroll
  for (int mt = 0; mt < 4; mt++) {
    float v = l_mt[mt];
    v += __shfl_xor(v, 16);
    v += __shfl_xor(v, 32);
    l_mt[mt] = v;
  }
  float* lred = (float*)(sm + 24576);  // [4][64]
  if (quad == 0) {
#pragma unroll
    for (int mt = 0; mt < 4; mt++)
      lred[wave * 64 + mt * 16 + l15] = l_mt[mt];
  }
  // partial O (bf16) into wave's own region [64][64]
#pragma unroll
  for (int mt = 0; mt < 4; mt++)
#pragma unroll
    for (int nt = 0; nt < 4; nt++)
#pragma unroll
      for (int reg = 0; reg < 4; reg++)
        wb[(mt * 16 + quad * 4 + reg) * 64 + nt * 16 + l15] =
            f2bf(oacc[mt][nt][reg]);
  __syncthreads();

  const int q = tid >> 2, dg = (tid & 3) * 16;
  const float inv =
      1.0f / (lred[q] + lred[64 + q] + lred[128 + q] + lred[192 + q]);
  float o[16];
#pragma unroll
  for (int j = 0; j < 16; j++) o[j] = 0.f;
#pragma unroll
  for (int w = 0; w < 4; w++) {
    const bf16x8 a = *(const bf16x8*)(sm + w * 6144 + q * 64 + dg);
    const bf16x8 b = *(const bf16x8*)(sm + w * 6144 + q * 64 + dg + 8);
#pragma unroll
    for (int j = 0; j < 8; j++) {
      o[j] += (float)a[j];
      o[8 + j] += (float)b[j];
    }
  }
  bf16x8 r0, r1;
#pragma unroll
  for (int j = 0; j < 8; j++) {
    r0[j] = f2bf(o[j] * inv);
    r1[j] = f2bf(o[8 + j] * inv);
  }
  bf16_t* outp =
      attnA + ((size_t)(bq * 2048 + qtile * 64 + q)) * 768 + h * 64 + dg;
  *(bf16x8*)outp = r0;
  *(bf16x8*)(outp + 8) = r1;
}

// ---------------------------------------------------------------------------
extern "C" void kernel_launch(void* const* d_in, const int* in_sizes, int n_in,
                              void* d_out, int out_size, void* d_ws,
                              size_t ws_size, hipStream_t stream) {
  const float* hs  = (const float*)d_in[0];
  const float* wq  = (const float*)d_in[1];
  const float* bq  = (const float*)d_in[2];
  const float* wk  = (const float*)d_in[3];
  const float* bk  = (const float*)d_in[4];
  const float* wv  = (const float*)d_in[5];
  const float* bv  = (const float*)d_in[6];
  const float* wo  = (const float*)d_in[7];
  const float* bo  = (const float*)d_in[8];
  const float* ab  = (const float*)d_in[9];
  const float* g1  = (const float*)d_in[10];
  const float* be1 = (const float*)d_in[11];
  const float* g3  = (const float*)d_in[12];
  const float* be3 = (const float*)d_in[13];
  const float* w1  = (const float*)d_in[14];
  const float* b1  = (const float*)d_in[15];
  const float* w2  = (const float*)d_in[16];
  const float* b2  = (const float*)d_in[17];

  char* ws = (char*)d_ws;
  size_t off = 0;
  auto alloc = [&](size_t bytes) -> void* {
    void* p = ws + off;
    off += (bytes + 255) & ~(size_t)255;
    return p;
  };
  bf16_t* wqkvT = (bf16_t*)alloc((size_t)2304 * 768 * 2);
  bf16_t* woT   = (bf16_t*)alloc((size_t)768 * 768 * 2);
  bf16_t* w1T   = (bf16_t*)alloc((size_t)3072 * 768 * 2);
  bf16_t* w2T   = (bf16_t*)alloc((size_t)768 * 3072 * 2);
  bf16_t* ni    = (bf16_t*)alloc((size_t)4096 * 768 * 2);
  bf16_t* qhB   = (bf16_t*)alloc((size_t)24 * 2048 * 64 * 2);
  bf16_t* khB   = (bf16_t*)alloc((size_t)24 * 2048 * 64 * 2);
  bf16_t* vtB   = (bf16_t*)alloc((size_t)24 * 64 * 2048 * 2);
  bf16_t* attnA = (bf16_t*)alloc((size_t)4096 * 768 * 2);
  float*  resid1 = (float*)alloc((size_t)4096 * 768 * 4);
  bf16_t* ffn1o = qhB;  // overlay: q/k/v/attn region dead by FFN1 time

  // prep: all transposes + LN1, one dispatch
  PrepP pp = {wq, wk, wv, wo, w1, w2, wqkvT, woT, w1T, w2T, hs, g1, be1, ni};
  k_prep<<<11008, 256, 0, stream>>>(pp);

  // QKV (fused, N=2304): bias, q*0.125*log2e, p-RoPE, head-layout scatter
  GemmP gqkv = {ni, wqkvT, 4096, 2304, 768, 0,
                bq, bk, bv, nullptr, qhB, khB, vtB};
  k_gemm<<<dim3(18, 32), 256, 0, stream>>>(gqkv);

  // flash attention v7 (K 3-ring / V 3-ring, vmcnt(6) pipeline)
  k_flash<<<dim3(32, 24), 256, 0, stream>>>(qhB, khB, vtB, ab, attnA);

  // attn @ wo + bo + residual(hidden) -> resid1 (fp32)
  k_gemm64<<<dim3(12, 64), 256, 0, stream>>>(attnA, woT, 768, 768, bo, hs,
                                             resid1);

  // LN3
  k_layernorm<<<4096, 256, 0, stream>>>(resid1, g3, be3, ni);

  // FFN1 + exact GELU -> bf16
  GemmP gf1 = {ni, w1T, 4096, 3072, 768, 2,
               b1, nullptr, nullptr, nullptr, ffn1o, nullptr, nullptr};
  k_gemm<<<dim3(24, 32), 256, 0, stream>>>(gf1);

  // FFN2 + b2 + residual -> d_out (fp32 [4096][768])
  k_gemm64<<<dim3(12, 64), 256, 0, stream>>>(ffn1o, w2T, 768, 3072, b2,
                                             resid1, (float*)d_out);
}